// Round 5
// baseline (395.685 us; speedup 1.0000x reference)
//
#include <hip/hip_runtime.h>
#include <stdint.h>

// Problem constants (B,S,D,A fixed by the reference)
#define B_ 64
#define S_ 2048
#define D_ 512
#define A_ 256
#define TM 32          // tokens per tile
#define TPB 16         // tiles per block (block covers 512 tokens of one b)
#define NBLK 256       // B_*S_/(TM*TPB)
#define EPS 1e-7f

// s_waitcnt immediates (gfx9 encoding: vmcnt[3:0]|[15:14], exp[6:4], lgkm[11:8])
#define WAIT_LGKM0 0xC07F   // lgkmcnt(0), vmcnt=63 (untouched), exp=7
#define WAIT_VM0   0x0F70   // vmcnt(0),   lgkm=15 (untouched), exp=7

typedef short bf16x8 __attribute__((ext_vector_type(8)));
typedef float f32x4  __attribute__((ext_vector_type(4)));

// Workspace layout (bytes):
//  [0,      262144)  Wt    bf16 [A_][D_]   (W transposed, k-contiguous rows)
//  [262144, 786432)  part  f32  [NBLK][D_] (fully written every call)
//  [786432, 787456)  Zpart f32  [NBLK]
//  [787456, 787460)  mask-mode flag: 1 = byte mask, 0 = 4-byte mask
#define WS_WT   0
#define WS_PART 262144
#define WS_ZP   786432
#define WS_FLAG 787456

__device__ __forceinline__ uint32_t f32pair_to_bf16(float a, float b) {
  // round-to-nearest-even fp32 -> bf16, packed (a = low half / lower k index)
  uint32_t ua = __float_as_uint(a), ub = __float_as_uint(b);
  ua = (ua + 0x7fffu + ((ua >> 16) & 1u)) >> 16;
  ub = (ub + 0x7fffu + ((ub >> 16) & 1u)) & 0xffff0000u;
  return ua | ub;
}

// async global->LDS, 16B per lane; lds base wave-uniform (HW adds lane*16),
// global address per-lane. Verified-correct interleave (R4, absmax 9.8e-4).
__device__ __forceinline__ void gload_lds16(const float* g, float* l) {
  __builtin_amdgcn_global_load_lds(
      (const __attribute__((address_space(1))) uint32_t*)g,
      (__attribute__((address_space(3))) uint32_t*)l, 16, 0, 0);
}

// sum over the 16-lane DPP row via 4 VALU-latency DPP adds (all lanes get the sum)
__device__ __forceinline__ float row16_sum(float x) {
  int v = __float_as_int(x);
  x += __int_as_float(__builtin_amdgcn_update_dpp(v, v, 0xB1, 0xF, 0xF, false));  // quad xor1
  v = __float_as_int(x);
  x += __int_as_float(__builtin_amdgcn_update_dpp(v, v, 0x4E, 0xF, 0xF, false));  // quad xor2
  v = __float_as_int(x);
  x += __int_as_float(__builtin_amdgcn_update_dpp(v, v, 0x141, 0xF, 0xF, false)); // half mirror
  v = __float_as_int(x);
  x += __int_as_float(__builtin_amdgcn_update_dpp(v, v, 0x128, 0xF, 0xF, false)); // row ror:8
  return x;
}

// Software barrier: NO vmcnt drain (the whole point — async gld queue stays live).
// lgkmcnt(0) makes this wave's LDS writes visible; counter is monotone, target
// advances by 8 (one increment per wave) per barrier instance.
__device__ __forceinline__ void soft_bar(int* cnt, int target) {
  __builtin_amdgcn_sched_barrier(0);
  __builtin_amdgcn_s_waitcnt(WAIT_LGKM0);
  if ((threadIdx.x & 63) == 0)
    __hip_atomic_fetch_add(cnt, 1, __ATOMIC_RELAXED, __HIP_MEMORY_SCOPE_WORKGROUP);
  while (__hip_atomic_load(cnt, __ATOMIC_RELAXED, __HIP_MEMORY_SCOPE_WORKGROUP) < target)
    __builtin_amdgcn_s_sleep(1);
  __builtin_amdgcn_sched_barrier(0);
}

__global__ __launch_bounds__(256) void prep_kernel(
    const float* __restrict__ W, const void* __restrict__ mask,
    uint16_t* __restrict__ Wt, int* __restrict__ flag)
{
  int i = blockIdx.x * 256 + threadIdx.x;
  if (i < A_ * D_) {
    int a = i >> 9;            // D_=512
    int d = i & (D_ - 1);
    uint32_t u = __float_as_uint(W[d * A_ + a]);
    u = (u + 0x7fffu + ((u >> 16) & 1u)) >> 16;
    Wt[i] = (uint16_t)u;       // Wt[a][d]
  }
  // Mask encoding detection (one wave, first 4KB; see R0 notes)
  if (blockIdx.x == 0 && threadIdx.x < 64) {
    const uint32_t* mw = (const uint32_t*)mask;
    int hit = 0;
    for (int k = 0; k < 16; ++k) {
      uint32_t v = mw[threadIdx.x + 64 * k];
      uint32_t b0 = v & 0xff, b1 = (v >> 8) & 0xff, b2 = (v >> 16) & 0xff, b3 = v >> 24;
      if (b0 <= 1u && b1 <= 1u && b2 <= 1u && b3 <= 1u && (b1 | b2 | b3)) hit = 1;
    }
    hit = __any(hit);
    if (threadIdx.x == 0) *flag = hit ? 1 : 0;
  }
}

__global__ __launch_bounds__(512, 2) void att_main(
    const float* __restrict__ x, const void* __restrict__ mask,
    const float* __restrict__ bias, const float* __restrict__ uvec,
    const uint16_t* __restrict__ Wt, float* __restrict__ part,
    float* __restrict__ Zpart, const int* __restrict__ flag)
{
  // xf: fp32 staging, PER-WAVE OWNED rows (wave w owns rows 4w..4w+3 of every
  // tile) -> gld->pack sync is wave-private vmcnt, no cross-wave hazard.
  __shared__ float xf[TM * D_];          // 64 KB
  // double-buffered XOR-swizzled bf16 tile: chunk c of row stored at c^(row&7)
  __shared__ uint16_t xs[2][TM * D_];    // 2 x 32 KB
  __shared__ float sp[8][TM];            // per-wave score partials
  __shared__ float me[TM * TPB];         // mask as 0/1 float for block's 512 tokens
  __shared__ int bcnt;                   // soft-barrier counter

  const int tid = threadIdx.x;
  const int l  = tid & 63, w  = tid >> 6;   // 8 waves
  const int lr = l & 15,   lg = l >> 4;
  const int bx = blockIdx.x;
  const int b  = bx >> 2;                   // 4 blocks per batch row
  const int s0 = (bx & 3) * (TM * TPB);
  const float* xb = x + ((size_t)b * S_ + s0) * D_;

  if (tid == 0) bcnt = 0;
  __syncthreads();            // only hard barrier (before any async load)
  int bt = 8;                 // next soft-barrier target

  const int mflag = *flag;

  // ---- mask -> LDS (once per block) ----
  {
    int midx = b * S_ + s0 + tid;
    int mv = mflag ? (((const unsigned char*)mask)[midx] != 0)
                   : (((const int*)mask)[midx] != 0);
    me[tid] = mv ? 1.0f : 0.0f;
  }

  // ---- Wt B-fragments resident in VGPRs for the whole block (128 VGPRs) ----
  bf16x8 bfr[32];
  {
    const uint16_t* wtb = Wt + (size_t)(w * 32 + lr) * D_;
    #pragma unroll
    for (int ks = 0; ks < 16; ++ks)
      #pragma unroll
      for (int nt = 0; nt < 2; ++nt)
        bfr[ks * 2 + nt] = *(const bf16x8*)(wtb + nt * 16 * D_ + ks * 32 + lg * 8);
  }
  float bn[2], un[2];
  #pragma unroll
  for (int nt = 0; nt < 2; ++nt) {
    int n = w * 32 + nt * 16 + lr;
    bn[nt] = bias[n];
    un[nt] = uvec[n];
  }

  float num_acc = 0.0f;   // this thread's d-column (d = tid) over all 512 tokens
  float zacc    = 0.0f;   // Z partial (w==0, l==0)

  // ---- prologue: load+pack tile 0, issue tile 1 ----
  #pragma unroll
  for (int i = 0; i < 8; ++i) {
    int row = w * 4 + (i >> 1), h = i & 1;
    gload_lds16(xb + row * D_ + (2 * l + h) * 4, &xf[row * D_ + h * 256]);
  }
  __builtin_amdgcn_s_waitcnt(WAIT_VM0);   // own 8 loads done (others keep running)
  #pragma unroll
  for (int c = 0; c < 4; ++c) {
    int row = w * 4 + c;
    float4 lo = *(const float4*)&xf[row * D_ + l * 4];
    float4 hi = *(const float4*)&xf[row * D_ + 256 + l * 4];
    uint4 pk;
    pk.x = f32pair_to_bf16(lo.x, lo.y);
    pk.y = f32pair_to_bf16(lo.z, lo.w);
    pk.z = f32pair_to_bf16(hi.x, hi.y);
    pk.w = f32pair_to_bf16(hi.z, hi.w);
    *(uint4*)(&xs[0][row * D_ + ((l ^ (row & 7)) * 8)]) = pk;
  }
  __builtin_amdgcn_sched_barrier(0);
  __builtin_amdgcn_s_waitcnt(WAIT_LGKM0); // pack reads retired before xf overwrite
  {
    const float* xt = xb + (size_t)TM * D_;
    #pragma unroll
    for (int i = 0; i < 8; ++i) {
      int row = w * 4 + (i >> 1), h = i & 1;
      gload_lds16(xt + row * D_ + (2 * l + h) * 4, &xf[row * D_ + h * 256]);
    }
  }
  soft_bar(&bcnt, bt); bt += 8;           // xs[0] + me visible to all waves

  #pragma unroll 2
  for (int t = 0; t < TPB; ++t) {
    const uint16_t* buf = xs[t & 1];

    // ---- MFMA: A from bf16 LDS, B from registers ----
    f32x4 acc[2][2];
    #pragma unroll
    for (int mt = 0; mt < 2; ++mt)
      #pragma unroll
      for (int nt = 0; nt < 2; ++nt)
        acc[mt][nt] = (f32x4){0.f, 0.f, 0.f, 0.f};

    #pragma unroll
    for (int ks = 0; ks < 16; ++ks) {
      bf16x8 af[2];
      #pragma unroll
      for (int mt = 0; mt < 2; ++mt)
        af[mt] = *(const bf16x8*)(&buf[(mt * 16 + lr) * D_ + (((ks * 4 + lg) ^ (lr & 7)) * 8)]);
      #pragma unroll
      for (int mt = 0; mt < 2; ++mt)
        #pragma unroll
        for (int nt = 0; nt < 2; ++nt)
          acc[mt][nt] = __builtin_amdgcn_mfma_f32_16x16x32_bf16(af[mt], bfr[ks * 2 + nt], acc[mt][nt], 0, 0, 0);
    }

    // ---- epilogue: tanh(acc+bias)*u, DPP-reduce over this wave's 32 a ----
    #pragma unroll
    for (int mt = 0; mt < 2; ++mt) {
      #pragma unroll
      for (int r = 0; r < 4; ++r) {
        float ssum = 0.0f;
        #pragma unroll
        for (int nt = 0; nt < 2; ++nt) {
          float vv = acc[mt][nt][r] + bn[nt];
          float av = fabsf(vv);
          float e2 = __expf(-2.0f * av);
          float th = 1.0f - 2.0f * e2 * __builtin_amdgcn_rcpf(1.0f + e2);
          ssum += copysignf(th, vv) * un[nt];
        }
        ssum = row16_sum(ssum);
        if (lr == 0) sp[w][mt * 16 + lg * 4 + r] = ssum;
      }
    }

    soft_bar(&bcnt, bt); bt += 8;   // barB: sp(t) visible (no vmcnt drain!)

    // ---- e_s per wave (lanes 0..31), Z partial in wave 0 ----
    float eval = 0.0f;
    if (l < 32) {
      float sc = 0.0f;
      #pragma unroll
      for (int ww = 0; ww < 8; ++ww) sc += sp[ww][l];
      eval = me[t * TM + l] * __expf(sc);
    }
    if (w == 0 && l < 32) {
      float tot = eval;
      tot += __shfl_xor(tot, 1);
      tot += __shfl_xor(tot, 2);
      tot += __shfl_xor(tot, 4);
      tot += __shfl_xor(tot, 8);
      tot += __shfl_xor(tot, 16);
      if (l == 0) zacc += tot;
    }

    // ---- numerator: num_acc += sum_s e_s * x[s][d], d = tid (bf16 tile) ----
    {
      int cw = tid >> 3, wo = (tid & 7) >> 1;
      #pragma unroll
      for (int s = 0; s < TM; ++s) {
        float e = __int_as_float(__builtin_amdgcn_readlane(__float_as_int(eval), s));
        uint32_t vv = *(const uint32_t*)(&buf[s * D_ + (cw ^ (s & 7)) * 8 + wo * 2]);
        float xv = (tid & 1) ? __uint_as_float(vv & 0xffff0000u)
                             : __uint_as_float(vv << 16);
        num_acc = fmaf(e, xv, num_acc);
      }
    }

    // ---- wave-private: wait own gld(t+1), pack it, issue gld(t+2) ----
    if (t + 1 < TPB) {
      __builtin_amdgcn_s_waitcnt(WAIT_VM0);   // own 8 loads (issued 1 iter ago)
      uint16_t* nb = xs[(t + 1) & 1];
      #pragma unroll
      for (int c = 0; c < 4; ++c) {
        int row = w * 4 + c;
        float4 lo = *(const float4*)&xf[row * D_ + l * 4];
        float4 hi = *(const float4*)&xf[row * D_ + 256 + l * 4];
        uint4 pk;
        pk.x = f32pair_to_bf16(lo.x, lo.y);
        pk.y = f32pair_to_bf16(lo.z, lo.w);
        pk.z = f32pair_to_bf16(hi.x, hi.y);
        pk.w = f32pair_to_bf16(hi.z, hi.w);
        *(uint4*)(&nb[row * D_ + ((l ^ (row & 7)) * 8)]) = pk;
      }
      __builtin_amdgcn_sched_barrier(0);
      __builtin_amdgcn_s_waitcnt(WAIT_LGKM0); // pack reads retired before overwrite
      if (t + 2 < TPB) {
        const float* xt = xb + (size_t)(t + 2) * TM * D_;
        #pragma unroll
        for (int i = 0; i < 8; ++i) {
          int row = w * 4 + (i >> 1), h = i & 1;
          gload_lds16(xt + row * D_ + (2 * l + h) * 4, &xf[row * D_ + h * 256]);
        }
      }
    }

    soft_bar(&bcnt, bt); bt += 8;   // barA: xs[(t+1)&1] visible to all waves
  }

  part[(size_t)bx * D_ + tid] = num_acc;
  if (tid == 0) Zpart[bx] = zacc;
}

__global__ __launch_bounds__(256) void scale_kernel(
    const float* __restrict__ part, const float* __restrict__ Zpart,
    float* __restrict__ out)
{
  int idx = blockIdx.x * 256 + threadIdx.x;   // 32768 = B_*D_
  int b = idx >> 9;
  int d = idx & (D_ - 1);
  float s = 0.0f, z = 0.0f;
  #pragma unroll
  for (int g = 0; g < 4; ++g) {
    s += part[(size_t)(b * 4 + g) * D_ + d];
    z += Zpart[b * 4 + g];
  }
  out[idx] = s / (z + EPS);
}

extern "C" void kernel_launch(void* const* d_in, const int* in_sizes, int n_in,
                              void* d_out, int out_size, void* d_ws, size_t ws_size,
                              hipStream_t stream)
{
  const float* x    = (const float*)d_in[0];
  const void*  mask = d_in[1];
  const float* W    = (const float*)d_in[2];
  const float* bias = (const float*)d_in[3];
  const float* u    = (const float*)d_in[4];
  float* out = (float*)d_out;

  char* ws = (char*)d_ws;
  uint16_t* Wt  = (uint16_t*)(ws + WS_WT);
  float* part   = (float*)(ws + WS_PART);
  float* Zpart  = (float*)(ws + WS_ZP);
  int*   flag   = (int*)(ws + WS_FLAG);

  prep_kernel<<<(A_ * D_ + 255) / 256, 256, 0, stream>>>(W, mask, Wt, flag);
  att_main<<<NBLK, 512, 0, stream>>>(x, mask, bias, u, Wt, part, Zpart, flag);
  scale_kernel<<<(B_ * D_ + 255) / 256, 256, 0, stream>>>(part, Zpart, out);
}